// Round 10
// baseline (525.439 us; speedup 1.0000x reference)
//
#include <hip/hip_runtime.h>
#include <cstdint>
#include <cstddef>

#define NN 100000
#define NE 1600000
#define IND 128
#define OUTD 64
#define MDIM 16
#define GHID 64
#define NPART 12500  // NN / 8 XCDs

#define CVT_BLKS (NE / 256)                 // 6250
#define MPREP_BLKS ((NN * MDIM / 2) / 256)  // 3125
#define PREP_BLKS 88                        // 88*256 = 22528 exactly
#define GMM_BLKS ((NN + 63) / 64)           // 1563
#define FILL_BLKS (8 * ((NE + 2047) / 2048))

typedef __attribute__((ext_vector_type(8))) short bf8_t;
typedef __attribute__((ext_vector_type(4))) float f4_t;
typedef __attribute__((ext_vector_type(2))) float f2v;
typedef unsigned short ushort_t;

// ---- bf16 helpers (RNE pack, exact unpack) --------------------------------
__device__ inline unsigned f2bf_pack(float a, float b) {
    unsigned ua = __float_as_uint(a);
    unsigned ub = __float_as_uint(b);
    unsigned ra = (ua + 0x7fffu + ((ua >> 16) & 1u)) >> 16;
    unsigned rb = (ub + 0x7fffu + ((ub >> 16) & 1u)) >> 16;
    return ra | (rb << 16);
}
__device__ inline ushort_t f2bf1(float f) {
    unsigned u = __float_as_uint(f);
    return (ushort_t)((u + 0x7fffu + ((u >> 16) & 1u)) >> 16);
}
__device__ inline float2 bf2x(unsigned u) {
    return make_float2(__uint_as_float(u << 16),
                       __uint_as_float(u & 0xffff0000u));
}

// ---------------- fused front: cvt(+inline detect) | mprep | prep ----------
__global__ __launch_bounds__(256) void k_front(
    const void* __restrict__ ei, int* __restrict__ s32,
    int* __restrict__ d32, int* __restrict__ count,
    const float* __restrict__ motif, unsigned* __restrict__ mb,
    const float* __restrict__ cw, const float* __restrict__ hw,
    const float* __restrict__ w1, unsigned* __restrict__ btf) {
    unsigned b = blockIdx.x;
    if (b < CVT_BLKS) {
        int lane = threadIdx.x & 63;
        const unsigned long long* p = (const unsigned long long*)ei;
        unsigned long long v = p[(size_t)lane * (NE / 64)];
        bool hi0 = (v >> 32) == 0ull;
        unsigned long long bal = __ballot(hi0);
        bool is64 = (bal == ~0ull);
        int e = b * 256 + threadIdx.x;  // NE % 256 == 0: always in range
        int s, d;
        if (is64) {
            s = (int)((const long long*)ei)[e];
            d = (int)((const long long*)ei)[NE + e];
        } else {
            s = ((const int*)ei)[e];
            d = ((const int*)ei)[NE + e];
        }
        s32[e] = s;
        d32[e] = d;
        atomicAdd(&count[d], 1);
    } else if (b < CVT_BLKS + MPREP_BLKS) {
        int i = (b - CVT_BLKS) * 256 + threadIdx.x;  // exact
        const float2 v = ((const float2*)motif)[i];
        mb[i] = f2bf_pack(v.x, v.y);
    } else {
        int i = (b - CVT_BLKS - MPREP_BLKS) * 256 + threadIdx.x;  // exact
        const float* W;
        int ncols, local, kk, nt;
        int w, lane;
        if (i < 16384) {
            W = cw + (i >> 13) * 16384; ncols = 128; local = i & 8191;
            w = local & 3; lane = (local >> 2) & 63;
            kk = (local >> 8) & 3; nt = local >> 10;
        } else if (i < 20480) {
            W = hw; ncols = 64; local = i - 16384;
            w = local & 3; lane = (local >> 2) & 63;
            kk = (local >> 8) & 3; nt = local >> 10;
        } else {
            W = w1; ncols = 64; local = i - 20480;
            w = local & 3; lane = (local >> 2) & 63;
            kk = (local >> 8) & 1; nt = local >> 9;
        }
        int n = nt * 16 + (lane & 15);
        int k = kk * 32 + (lane >> 4) * 8 + 2 * w;
        btf[i] = f2bf_pack(W[k * ncols + n], W[(k + 1) * ncols + n]);
    }
}

// ---------------- counting-sort scan (exclusive prefix of count) -----------
__global__ __launch_bounds__(256) void k_scan1(const int* __restrict__ count,
                                               int* __restrict__ rs,
                                               int* __restrict__ bsum) {
    __shared__ int sd[256];
    int tid = threadIdx.x;
    int base = blockIdx.x * 2048 + tid * 8;
    int loc[8]; int s = 0;
#pragma unroll
    for (int i = 0; i < 8; i++) {
        int idx = base + i;
        int v = (idx < NN) ? count[idx] : 0;
        loc[i] = s; s += v;
    }
    sd[tid] = s; __syncthreads();
    for (int off = 1; off < 256; off <<= 1) {
        int t = (tid >= off) ? sd[tid - off] : 0;
        __syncthreads();
        sd[tid] += t;
        __syncthreads();
    }
    int texcl = sd[tid] - s;
    if (tid == 255) bsum[blockIdx.x] = sd[255];
#pragma unroll
    for (int i = 0; i < 8; i++) {
        int idx = base + i;
        if (idx < NN) rs[idx] = texcl + loc[i];
    }
}

__global__ __launch_bounds__(64) void k_scan2(const int* __restrict__ bsum,
                                              int* __restrict__ boffs) {
    int tid = threadIdx.x;
    int v = (tid < 49) ? bsum[tid] : 0;
    int x = v;
#pragma unroll
    for (int off = 1; off < 64; off <<= 1) {
        int t = __shfl_up(x, off, 64);
        if (tid >= off) x += t;
    }
    boffs[tid] = x - v;  // exclusive
}

__global__ __launch_bounds__(256) void k_scan3(int* __restrict__ rs,
                                               const int* __restrict__ boffs,
                                               int* __restrict__ cursor) {
    int i = blockIdx.x * 256 + threadIdx.x;
    if (i < NN) {
        int v = rs[i] + boffs[i >> 11];
        rs[i] = v;
        cursor[i] = v;
    }
}

// ---------------- fill CSR, XCD-partitioned, standalone (low VGPR) ---------
// R9 post-mortem: fusing the GEMM here set VGPR=56 -> occupancy 38% and the
// atomic/scatter latency chain ran exposed (91.5us). Standalone keeps VGPR
// low for 8-waves TLP. Micro-fix: the 8 partition-scan d32 loads are batched
// upfront (8 coalesced loads in flight) instead of read->test->atomic serial.
__global__ __launch_bounds__(256) void k_fill(const int* __restrict__ s32,
                                              const int* __restrict__ d32,
                                              int* __restrict__ cursor,
                                              int2* __restrict__ es) {
    int p = blockIdx.x & 7;
    int base = (blockIdx.x >> 3) * 2048;
    int ds[8];
#pragma unroll
    for (int it = 0; it < 8; it++) {
        int e = base + it * 256 + threadIdx.x;
        ds[it] = (e < NE) ? d32[e] : -1;
    }
#pragma unroll
    for (int it = 0; it < 8; it++) {
        int d = ds[it];
        if ((unsigned)d / NPART != (unsigned)p) continue;  // -1 never matches
        int e = base + it * 256 + threadIdx.x;
        int s = s32[e];
        int pos = atomicAdd(&cursor[d], 1);
        es[pos] = make_int2(s, d);
    }
}

// ---------------- MFMA GEMM (layer 0): xw_bf16 = round_bf16(x_f32) @ W -----
// Standalone (~17us): both fusion homes measured as net losers (R8: gate
// occupancy 37%; R9: fill occupancy 38%).
__global__ __launch_bounds__(256) void k_mm_conv_f32(
    const float* __restrict__ A, const uint4* __restrict__ btf,
    ushort_t* __restrict__ outb) {
    int w = threadIdx.x >> 6, lane = threadIdx.x & 63;
    int mh = w & 1, nh = w >> 1;
    int quad = lane >> 4, lx = lane & 15;
    int m0 = blockIdx.x * 64 + mh * 32;
    bf8_t a[2][4];
#pragma unroll
    for (int mt = 0; mt < 2; mt++) {
        int row = m0 + mt * 16 + lx;
        row = row < NN ? row : NN - 1;
#pragma unroll
        for (int kk = 0; kk < 4; kk++) {
            const float4* ap =
                (const float4*)(A + (size_t)row * 128 + kk * 32 + quad * 8);
            float4 u0 = ap[0], u1 = ap[1];
            union { unsigned u[4]; bf8_t v; } t;
            t.u[0] = f2bf_pack(u0.x, u0.y);
            t.u[1] = f2bf_pack(u0.z, u0.w);
            t.u[2] = f2bf_pack(u1.x, u1.y);
            t.u[3] = f2bf_pack(u1.z, u1.w);
            a[mt][kk] = t.v;
        }
    }
    f4_t acc[2][4];
#pragma unroll
    for (int mt = 0; mt < 2; mt++)
#pragma unroll
        for (int nt = 0; nt < 4; nt++) acc[mt][nt] = (f4_t){0.f, 0.f, 0.f, 0.f};
#pragma unroll
    for (int nt = 0; nt < 4; nt++) {
        int ntg = nh * 4 + nt;
#pragma unroll
        for (int kk = 0; kk < 4; kk++) {
            union { uint4 u; bf8_t v; } bb;
            bb.u = btf[(ntg * 4 + kk) * 64 + lane];
            acc[0][nt] = __builtin_amdgcn_mfma_f32_16x16x32_bf16(
                a[0][kk], bb.v, acc[0][nt], 0, 0, 0);
            acc[1][nt] = __builtin_amdgcn_mfma_f32_16x16x32_bf16(
                a[1][kk], bb.v, acc[1][nt], 0, 0, 0);
        }
    }
#pragma unroll
    for (int mt = 0; mt < 2; mt++)
#pragma unroll
        for (int nt = 0; nt < 4; nt++) {
#pragma unroll
            for (int r = 0; r < 4; r++) {
                int row = m0 + mt * 16 + quad * 4 + r;
                if (row < NN)
                    outb[(size_t)row * 128 + (nh * 4 + nt) * 16 + lx] =
                        f2bf1(acc[mt][nt][r]);
            }
        }
}

// ---------------- edge gate via MFMA: h = [mu|mv|f2|f3] @ W1 + b1 ----------
// One wave = 16 edges. Lane (quad,lx): loads bf16 motif row-half (16B uint4 =
// the a0 MFMA fragment DIRECTLY) of node (quad<2?s:d), half = quad&1, from
// the 3.2MB L2-resident packed table. Packed shfl_xor(.,32) swaps mu<->mv.
__global__ __launch_bounds__(256) void k_gate(
    const unsigned* __restrict__ mb, const int2* __restrict__ es,
    const uint4* __restrict__ w1f, const float* __restrict__ b1,
    const float* __restrict__ w2, const float* __restrict__ b2,
    float* __restrict__ g_s) {
    int wv = threadIdx.x >> 6, lane = threadIdx.x & 63;
    int e0 = (blockIdx.x * 4 + wv) * 16;
    int quad = lane >> 4, lx = lane & 15;
    int2 sd = es[e0 + lx];
    int node = (quad < 2) ? sd.x : sd.y;
    int half = quad & 1;
    uint4 mu = *(const uint4*)(mb + (unsigned)(node << 3) + (half << 2));
    union { unsigned u[4]; bf8_t v; } a0, a1;
    a0.u[0] = mu.x; a0.u[1] = mu.y; a0.u[2] = mu.z; a0.u[3] = mu.w;
    unsigned o0 = __shfl_xor(mu.x, 32, 64), o1 = __shfl_xor(mu.y, 32, 64);
    unsigned o2 = __shfl_xor(mu.z, 32, 64), o3 = __shfl_xor(mu.w, 32, 64);
    float own[8], oth[8];
    {
        float2 t;
        t = bf2x(mu.x); own[0] = t.x; own[1] = t.y;
        t = bf2x(mu.y); own[2] = t.x; own[3] = t.y;
        t = bf2x(mu.z); own[4] = t.x; own[5] = t.y;
        t = bf2x(mu.w); own[6] = t.x; own[7] = t.y;
        t = bf2x(o0); oth[0] = t.x; oth[1] = t.y;
        t = bf2x(o1); oth[2] = t.x; oth[3] = t.y;
        t = bf2x(o2); oth[4] = t.x; oth[5] = t.y;
        t = bf2x(o3); oth[6] = t.x; oth[7] = t.y;
    }
    float f[8];
#pragma unroll
    for (int j = 0; j < 8; j++)
        f[j] = (quad < 2) ? fabsf(own[j] - oth[j]) : own[j] * oth[j];
#pragma unroll
    for (int q = 0; q < 4; q++) a1.u[q] = f2bf_pack(f[2 * q], f[2 * q + 1]);
    f4_t acc[4];
#pragma unroll
    for (int nt = 0; nt < 4; nt++) {
        float bi = b1[nt * 16 + lx];
        acc[nt] = (f4_t){bi, bi, bi, bi};
    }
#pragma unroll
    for (int nt = 0; nt < 4; nt++) {
        union { uint4 u; bf8_t v; } b0, bb1;
        b0.u = w1f[(nt * 2 + 0) * 64 + lane];
        bb1.u = w1f[(nt * 2 + 1) * 64 + lane];
        acc[nt] = __builtin_amdgcn_mfma_f32_16x16x32_bf16(a0.v, b0.v, acc[nt],
                                                          0, 0, 0);
        acc[nt] = __builtin_amdgcn_mfma_f32_16x16x32_bf16(a1.v, bb1.v, acc[nt],
                                                          0, 0, 0);
    }
    float p[4] = {0.f, 0.f, 0.f, 0.f};
#pragma unroll
    for (int nt = 0; nt < 4; nt++) {
        float w2v = w2[nt * 16 + lx];
#pragma unroll
        for (int r = 0; r < 4; r++)
            p[r] = fmaf(fmaxf(acc[nt][r], 0.0f), w2v, p[r]);
    }
#pragma unroll
    for (int m = 1; m < 16; m <<= 1) {
#pragma unroll
        for (int r = 0; r < 4; r++) p[r] += __shfl_xor(p[r], m, 64);
    }
    if (lx < 4) {
        float g = p[lx] + b2[0];
        g_s[e0 + quad * 4 + lx] = 1.0f / (1.0f + __expf(-g));
    }
}

// ---------------- deg = 1 + row-sum of sorted gates -> dinv (wave/node) ----
__global__ __launch_bounds__(256) void k_deg(const int* __restrict__ rowstart,
                                             const int* __restrict__ count,
                                             const float* __restrict__ g_s,
                                             float* __restrict__ dinv) {
    int n = blockIdx.x * 4 + (threadIdx.x >> 6);
    int lane = threadIdx.x & 63;
    if (n >= NN) return;
    int a = rowstart[n], cnt = count[n];
    float sum = 0.0f;
    for (int c = lane; c < cnt; c += 64) sum += g_s[a + c];
#pragma unroll
    for (int m = 1; m < 64; m <<= 1) sum += __shfl_xor(sum, m, 64);
    if (lane == 0) dinv[n] = rsqrtf(1.0f + sum);
}

// ---------------- g_s[e] *= dinv[src]*dinv[dst] (in-place, coalesced) ------
__global__ __launch_bounds__(256) void k_wnorm(const int2* __restrict__ es,
                                               const float* __restrict__ dinv,
                                               float* __restrict__ g_s) {
    int e = blockIdx.x * 256 + threadIdx.x;
    if (e >= NE) return;
    int2 sd = es[e];
    g_s[e] *= dinv[sd.x] * dinv[sd.y];
}

// ---------------- MFMA GEMM (layer 1): xw_bf16 = A_bf16 @ W ----------------
__global__ __launch_bounds__(256) void k_mm_conv(
    const ushort_t* __restrict__ A, const uint4* __restrict__ btf,
    ushort_t* __restrict__ outb) {
    int w = threadIdx.x >> 6, lane = threadIdx.x & 63;
    int mh = w & 1, nh = w >> 1;
    int quad = lane >> 4, lx = lane & 15;
    int m0 = blockIdx.x * 64 + mh * 32;
    bf8_t a[2][4];
#pragma unroll
    for (int mt = 0; mt < 2; mt++) {
        int row = m0 + mt * 16 + lx;
        row = row < NN ? row : NN - 1;
#pragma unroll
        for (int kk = 0; kk < 4; kk++)
            a[mt][kk] = *(const bf8_t*)(A + (size_t)row * 128 + kk * 32 + quad * 8);
    }
    f4_t acc[2][4];
#pragma unroll
    for (int mt = 0; mt < 2; mt++)
#pragma unroll
        for (int nt = 0; nt < 4; nt++) acc[mt][nt] = (f4_t){0.f, 0.f, 0.f, 0.f};
#pragma unroll
    for (int nt = 0; nt < 4; nt++) {
        int ntg = nh * 4 + nt;
#pragma unroll
        for (int kk = 0; kk < 4; kk++) {
            union { uint4 u; bf8_t v; } bb;
            bb.u = btf[(ntg * 4 + kk) * 64 + lane];
            acc[0][nt] = __builtin_amdgcn_mfma_f32_16x16x32_bf16(
                a[0][kk], bb.v, acc[0][nt], 0, 0, 0);
            acc[1][nt] = __builtin_amdgcn_mfma_f32_16x16x32_bf16(
                a[1][kk], bb.v, acc[1][nt], 0, 0, 0);
        }
    }
#pragma unroll
    for (int mt = 0; mt < 2; mt++)
#pragma unroll
        for (int nt = 0; nt < 4; nt++) {
#pragma unroll
            for (int r = 0; r < 4; r++) {
                int row = m0 + mt * 16 + quad * 4 + r;
                if (row < NN)
                    outb[(size_t)row * 128 + (nh * 4 + nt) * 16 + lx] =
                        f2bf1(acc[mt][nt][r]);
            }
        }
}

// ---------------- MFMA GEMM head: out = A_bf16 @ head_w + head_b (N=64) ----
__global__ __launch_bounds__(256) void k_mm_head(
    const ushort_t* __restrict__ A, const uint4* __restrict__ btf,
    const float* __restrict__ bias, float* __restrict__ out) {
    int w = threadIdx.x >> 6, lane = threadIdx.x & 63;
    int mh = w & 1, nh = w >> 1;
    int quad = lane >> 4, lx = lane & 15;
    int m0 = blockIdx.x * 64 + mh * 32;
    bf8_t a[2][4];
#pragma unroll
    for (int mt = 0; mt < 2; mt++) {
        int row = m0 + mt * 16 + lx;
        row = row < NN ? row : NN - 1;
#pragma unroll
        for (int kk = 0; kk < 4; kk++)
            a[mt][kk] = *(const bf8_t*)(A + (size_t)row * 128 + kk * 32 + quad * 8);
    }
    f4_t acc[2][2];
#pragma unroll
    for (int mt = 0; mt < 2; mt++)
#pragma unroll
        for (int nt = 0; nt < 2; nt++) acc[mt][nt] = (f4_t){0.f, 0.f, 0.f, 0.f};
#pragma unroll
    for (int nt = 0; nt < 2; nt++) {
        int ntg = nh * 2 + nt;
#pragma unroll
        for (int kk = 0; kk < 4; kk++) {
            union { uint4 u; bf8_t v; } bb;
            bb.u = btf[(ntg * 4 + kk) * 64 + lane];
            acc[0][nt] = __builtin_amdgcn_mfma_f32_16x16x32_bf16(
                a[0][kk], bb.v, acc[0][nt], 0, 0, 0);
            acc[1][nt] = __builtin_amdgcn_mfma_f32_16x16x32_bf16(
                a[1][kk], bb.v, acc[1][nt], 0, 0, 0);
        }
    }
#pragma unroll
    for (int mt = 0; mt < 2; mt++)
#pragma unroll
        for (int nt = 0; nt < 2; nt++) {
            int col = (nh * 2 + nt) * 16 + lx;
            float bs = bias[col];
#pragma unroll
            for (int r = 0; r < 4; r++) {
                int row = m0 + mt * 16 + quad * 4 + r;
                if (row < NN) out[(size_t)row * 64 + col] = acc[mt][nt][r] + bs;
            }
        }
}

// ---------------- fused gather(bf16) + bias + LN + relu + residual ---------
// Best-measured inner loop (R4/R6: 78.2-79.5us, VGPR 20). wave=node, lane=2
// channels, shfl broadcast, 8/4/1-deep bursts, 32-bit voffset gathers,
// pk_fma acc. R2/R4/R5: at random-gather throughput limit; don't touch the
// loop. Residual source: f32 x (layer 0) or bf16 xcb in-place (layer 1);
// the f32 xc stream is eliminated (R9: -20us, absmax 0.031->0.016).
__global__ __launch_bounds__(256) void k_aggr(
    const int* __restrict__ rowstart, const int* __restrict__ count,
    const int2* __restrict__ es, const float* __restrict__ w_s,
    const unsigned* __restrict__ xwb, const float* __restrict__ dinv,
    const float* __restrict__ xoldf, const unsigned* __restrict__ xoldb,
    unsigned* __restrict__ xnewb, const float* __restrict__ cb,
    const float* __restrict__ lg, const float* __restrict__ lb,
    const int res_f32) {
    int n = blockIdx.x * 4 + (threadIdx.x >> 6);
    int lane = threadIdx.x & 63;
    if (n >= NN) return;
    float dn = dinv[n];
    unsigned su = xwb[(unsigned)(n << 6) | lane];  // self-loop
    f2v acc;
    acc.x = __uint_as_float(su << 16) * (dn * dn);
    acc.y = __uint_as_float(su & 0xffff0000u) * (dn * dn);
    int start = rowstart[n], cnt = count[n];
    for (int c = 0; c < cnt; c += 64) {
        int rem = cnt - c;
        int sv = 0; float wv = 0.0f;
        if (lane < rem) {
            sv = es[start + c + lane].x;
            wv = w_s[start + c + lane];
        }
        int m = rem < 64 ? rem : 64;
        int j = 0;
        for (; j + 8 <= m; j += 8) {  // 8 independent gathers in flight
            unsigned u[8]; float w[8];
#pragma unroll
            for (int q = 0; q < 8; q++) {
                int s = __shfl(sv, j + q, 64);
                w[q] = __shfl(wv, j + q, 64);
                u[q] = xwb[(unsigned)(s << 6) | lane];
            }
#pragma unroll
            for (int q = 0; q < 8; q++) {
                f2v v;
                v.x = __uint_as_float(u[q] << 16);
                v.y = __uint_as_float(u[q] & 0xffff0000u);
                acc += v * w[q];
            }
        }
        for (; j + 4 <= m; j += 4) {
            unsigned u[4]; float w[4];
#pragma unroll
            for (int q = 0; q < 4; q++) {
                int s = __shfl(sv, j + q, 64);
                w[q] = __shfl(wv, j + q, 64);
                u[q] = xwb[(unsigned)(s << 6) | lane];
            }
#pragma unroll
            for (int q = 0; q < 4; q++) {
                f2v v;
                v.x = __uint_as_float(u[q] << 16);
                v.y = __uint_as_float(u[q] & 0xffff0000u);
                acc += v * w[q];
            }
        }
        for (; j < m; j++) {
            int s = __shfl(sv, j, 64);
            float w = __shfl(wv, j, 64);
            unsigned u = xwb[(unsigned)(s << 6) | lane];
            f2v v;
            v.x = __uint_as_float(u << 16);
            v.y = __uint_as_float(u & 0xffff0000u);
            acc += v * w;
        }
    }
    float2 cbv = ((const float2*)cb)[lane];
    acc.x += cbv.x; acc.y += cbv.y;
    float s1 = acc.x + acc.y, s2 = acc.x * acc.x + acc.y * acc.y;
#pragma unroll
    for (int mm = 1; mm < 64; mm <<= 1) {
        s1 += __shfl_xor(s1, mm, 64);
        s2 += __shfl_xor(s2, mm, 64);
    }
    float mean = s1 * (1.0f / 128.0f);
    float var = s2 * (1.0f / 128.0f) - mean * mean;
    float rstd = rsqrtf(var + 1e-5f);
    float2 lgv = ((const float2*)lg)[lane];
    float2 lbv = ((const float2*)lb)[lane];
    float y0 = fmaxf((acc.x - mean) * rstd * lgv.x + lbv.x, 0.0f);
    float y1 = fmaxf((acc.y - mean) * rstd * lgv.y + lbv.y, 0.0f);
    float2 xo;
    if (res_f32)
        xo = ((const float2*)xoldf)[(size_t)n * 64 + lane];
    else
        xo = bf2x(xoldb[(unsigned)(n << 6) | lane]);
    float o0 = xo.x + y0, o1 = xo.y + y1;
    xnewb[(size_t)n * 64 + lane] = f2bf_pack(o0, o1);
}

extern "C" void kernel_launch(void* const* d_in, const int* in_sizes, int n_in,
                              void* d_out, int out_size, void* d_ws,
                              size_t ws_size, hipStream_t stream) {
    const float* x = (const float*)d_in[0];
    const float* motif = (const float*)d_in[1];
    const void* ei = d_in[2];
    const float* gw1 = (const float*)d_in[3];
    const float* gb1 = (const float*)d_in[4];
    const float* gw2 = (const float*)d_in[5];
    const float* gb2 = (const float*)d_in[6];
    const float* cw = (const float*)d_in[7];   // [2,128,128]
    const float* cb = (const float*)d_in[8];   // [2,128]
    const float* lg = (const float*)d_in[9];
    const float* lb = (const float*)d_in[10];
    const float* hw = (const float*)d_in[11];  // [128,64]
    const float* hb = (const float*)d_in[12];
    float* out = (float*)d_out;

    float* ws = (float*)d_ws;
    size_t o = 0;
    float* dinv = ws + o; o += NN;
    int* flag = (int*)(ws + o); o += 64;  // unused (layout stability)
    int* count = (int*)(ws + o); o += NN;
    int* rowstart = (int*)(ws + o); o += NN;
    int* cursor = (int*)(ws + o); o += NN;
    int* bsum = (int*)(ws + o); o += 64;
    int* boffs = (int*)(ws + o); o += 64;
    int2* es = (int2*)(ws + o); o += 2 * (size_t)NE;
    float* g_s = ws + o; o += NE;
    unsigned* xwb = (unsigned*)(ws + o); o += (size_t)NN * 64;  // bf16 xw
    float* xc = ws + o; o += (size_t)NN * IND;  // hosts s32/d32 only
    unsigned* xcb = (unsigned*)(ws + o); o += (size_t)NN * 64;  // bf16 xc
    unsigned* btf = (unsigned*)(ws + o); o += 22528;            // frag-packed W
    unsigned* mb = (unsigned*)(ws + o); o += (size_t)NN * 8;    // bf16 motif
    (void)flag;

    int* s32 = (int*)xc;
    int* d32 = (int*)xc + NE;

    hipMemsetAsync(count, 0, NN * sizeof(int), stream);
    // fused: cvt (inline int64/int32 detect) | motif bf16 pack | weight pack
    k_front<<<CVT_BLKS + MPREP_BLKS + PREP_BLKS, 256, 0, stream>>>(
        ei, s32, d32, count, motif, mb, cw, hw, gw1, btf);

    // counting sort by dst -> CSR (shared by both layers)
    k_scan1<<<(NN + 2047) / 2048, 256, 0, stream>>>(count, rowstart, bsum);
    k_scan2<<<1, 64, 0, stream>>>(bsum, boffs);
    k_scan3<<<(NN + 255) / 256, 256, 0, stream>>>(rowstart, boffs, cursor);
    // CSR fill standalone (low VGPR -> high occupancy for atomic latency)
    k_fill<<<FILL_BLKS, 256, 0, stream>>>(s32, d32, cursor, es);
    // L0 GEMM standalone (~17us; fusion homes measured as net losers)
    k_mm_conv_f32<<<GMM_BLKS, 256, 0, stream>>>(x, (const uint4*)btf,
                                                (ushort_t*)xwb);

    // gate, deg, normalize in place
    k_gate<<<NE / 64, 256, 0, stream>>>(mb, es, (const uint4*)(btf + 20480),
                                        gb1, gw2, gb2, g_s);
    k_deg<<<(NN + 3) / 4, 256, 0, stream>>>(rowstart, count, g_s, dinv);
    k_wnorm<<<NE / 256, 256, 0, stream>>>(es, dinv, g_s);

    // layer 0: residual from f32 x, output bf16 only
    k_aggr<<<(NN + 3) / 4, 256, 0, stream>>>(rowstart, count, es, g_s, xwb,
                                             dinv, x, (const unsigned*)0, xcb,
                                             cb, lg, lb, 1);
    // layer 1: residual from bf16 xcb (in-place), f32 stream eliminated
    k_mm_conv<<<GMM_BLKS, 256, 0, stream>>>((const ushort_t*)xcb,
                                            (const uint4*)(btf + 8192),
                                            (ushort_t*)xwb);
    k_aggr<<<(NN + 3) / 4, 256, 0, stream>>>(rowstart, count, es, g_s, xwb,
                                             dinv, (const float*)0, xcb, xcb,
                                             cb + IND, lg + IND, lb + IND, 0);

    k_mm_head<<<GMM_BLKS, 256, 0, stream>>>((const ushort_t*)xcb,
                                            (const uint4*)(btf + 16384), hb,
                                            out);
}

// Round 11
// 517.968 us; speedup vs baseline: 1.0144x; 1.0144x over previous
//
#include <hip/hip_runtime.h>
#include <cstdint>
#include <cstddef>

#define NN 100000
#define NE 1600000
#define IND 128
#define OUTD 64
#define MDIM 16
#define GHID 64
#define NPART 12500  // NN / 8 XCDs

#define CVT_BLKS (NE / 256)                 // 6250
#define MPREP_BLKS ((NN * MDIM / 2) / 256)  // 3125
#define PREP_BLKS 88                        // 88*256 = 22528 exactly
#define GMM_BLKS ((NN + 63) / 64)           // 1563
#define FILL_BLKS (8 * ((NE + 2047) / 2048))
#define SCAN1_BLKS ((NN + 2047) / 2048)     // 49

typedef __attribute__((ext_vector_type(8))) short bf8_t;
typedef __attribute__((ext_vector_type(4))) float f4_t;
typedef __attribute__((ext_vector_type(2))) float f2v;
typedef unsigned short ushort_t;

// ---- bf16 helpers (RNE pack, exact unpack) --------------------------------
__device__ inline unsigned f2bf_pack(float a, float b) {
    unsigned ua = __float_as_uint(a);
    unsigned ub = __float_as_uint(b);
    unsigned ra = (ua + 0x7fffu + ((ua >> 16) & 1u)) >> 16;
    unsigned rb = (ub + 0x7fffu + ((ub >> 16) & 1u)) >> 16;
    return ra | (rb << 16);
}
__device__ inline ushort_t f2bf1(float f) {
    unsigned u = __float_as_uint(f);
    return (ushort_t)((u + 0x7fffu + ((u >> 16) & 1u)) >> 16);
}
__device__ inline float2 bf2x(unsigned u) {
    return make_float2(__uint_as_float(u << 16),
                       __uint_as_float(u & 0xffff0000u));
}

// ---------------- fused front: cvt(+inline detect) | mprep | prep ----------
__global__ __launch_bounds__(256) void k_front(
    const void* __restrict__ ei, int* __restrict__ s32,
    int* __restrict__ d32, int* __restrict__ count,
    const float* __restrict__ motif, unsigned* __restrict__ mb,
    const float* __restrict__ cw, const float* __restrict__ hw,
    const float* __restrict__ w1, unsigned* __restrict__ btf) {
    unsigned b = blockIdx.x;
    if (b < CVT_BLKS) {
        int lane = threadIdx.x & 63;
        const unsigned long long* p = (const unsigned long long*)ei;
        unsigned long long v = p[(size_t)lane * (NE / 64)];
        bool hi0 = (v >> 32) == 0ull;
        unsigned long long bal = __ballot(hi0);
        bool is64 = (bal == ~0ull);
        int e = b * 256 + threadIdx.x;  // NE % 256 == 0: always in range
        int s, d;
        if (is64) {
            s = (int)((const long long*)ei)[e];
            d = (int)((const long long*)ei)[NE + e];
        } else {
            s = ((const int*)ei)[e];
            d = ((const int*)ei)[NE + e];
        }
        s32[e] = s;
        d32[e] = d;
        atomicAdd(&count[d], 1);
    } else if (b < CVT_BLKS + MPREP_BLKS) {
        int i = (b - CVT_BLKS) * 256 + threadIdx.x;  // exact
        const float2 v = ((const float2*)motif)[i];
        mb[i] = f2bf_pack(v.x, v.y);
    } else {
        int i = (b - CVT_BLKS - MPREP_BLKS) * 256 + threadIdx.x;  // exact
        const float* W;
        int ncols, local, kk, nt;
        int w, lane;
        if (i < 16384) {
            W = cw + (i >> 13) * 16384; ncols = 128; local = i & 8191;
            w = local & 3; lane = (local >> 2) & 63;
            kk = (local >> 8) & 3; nt = local >> 10;
        } else if (i < 20480) {
            W = hw; ncols = 64; local = i - 16384;
            w = local & 3; lane = (local >> 2) & 63;
            kk = (local >> 8) & 3; nt = local >> 10;
        } else {
            W = w1; ncols = 64; local = i - 20480;
            w = local & 3; lane = (local >> 2) & 63;
            kk = (local >> 8) & 1; nt = local >> 9;
        }
        int n = nt * 16 + (lane & 15);
        int k = kk * 32 + (lane >> 4) * 8 + 2 * w;
        btf[i] = f2bf_pack(W[k * ncols + n], W[(k + 1) * ncols + n]);
    }
}

// ---------------- counting-sort scan (exclusive prefix of count) -----------
__global__ __launch_bounds__(256) void k_scan1(const int* __restrict__ count,
                                               int* __restrict__ rs,
                                               int* __restrict__ bsum) {
    __shared__ int sd[256];
    int tid = threadIdx.x;
    int base = blockIdx.x * 2048 + tid * 8;
    int loc[8]; int s = 0;
#pragma unroll
    for (int i = 0; i < 8; i++) {
        int idx = base + i;
        int v = (idx < NN) ? count[idx] : 0;
        loc[i] = s; s += v;
    }
    sd[tid] = s; __syncthreads();
    for (int off = 1; off < 256; off <<= 1) {
        int t = (tid >= off) ? sd[tid - off] : 0;
        __syncthreads();
        sd[tid] += t;
        __syncthreads();
    }
    int texcl = sd[tid] - s;
    if (tid == 255) bsum[blockIdx.x] = sd[255];
#pragma unroll
    for (int i = 0; i < 8; i++) {
        int idx = base + i;
        if (idx < NN) rs[idx] = texcl + loc[i];
    }
}

// ---------------- scan3: add block offset (self-computed) -> rs, cursor ----
// scan2 eliminated: block b needs only sum(bsum[j], j < b>>3) -- a 49-element
// masked wave-reduce each wave computes redundantly (bsum is L2-hot).
__global__ __launch_bounds__(256) void k_scan3(int* __restrict__ rs,
                                               const int* __restrict__ bsum,
                                               int* __restrict__ cursor) {
    int K = blockIdx.x >> 3;  // 256-node block never crosses a 2048 boundary
    int lane = threadIdx.x & 63;
    int v = (lane < K) ? bsum[lane] : 0;  // K <= 48 < 64
#pragma unroll
    for (int m = 1; m < 64; m <<= 1) v += __shfl_xor(v, m, 64);
    int i = blockIdx.x * 256 + threadIdx.x;
    if (i < NN) {
        int t = rs[i] + v;
        rs[i] = t;
        cursor[i] = t;
    }
}

// ---------------- fill CSR, XCD-partitioned, standalone (low VGPR) ---------
__global__ __launch_bounds__(256) void k_fill(const int* __restrict__ s32,
                                              const int* __restrict__ d32,
                                              int* __restrict__ cursor,
                                              int2* __restrict__ es) {
    int p = blockIdx.x & 7;
    int base = (blockIdx.x >> 3) * 2048;
    int ds[8];
#pragma unroll
    for (int it = 0; it < 8; it++) {
        int e = base + it * 256 + threadIdx.x;
        ds[it] = (e < NE) ? d32[e] : -1;
    }
#pragma unroll
    for (int it = 0; it < 8; it++) {
        int d = ds[it];
        if ((unsigned)d / NPART != (unsigned)p) continue;  // -1 never matches
        int e = base + it * 256 + threadIdx.x;
        int s = s32[e];
        int pos = atomicAdd(&cursor[d], 1);
        es[pos] = make_int2(s, d);
    }
}

// ---------------- MFMA GEMM (layer 0): xw_bf16 = round_bf16(x_f32) @ W -----
__global__ __launch_bounds__(256) void k_mm_conv_f32(
    const float* __restrict__ A, const uint4* __restrict__ btf,
    ushort_t* __restrict__ outb) {
    int w = threadIdx.x >> 6, lane = threadIdx.x & 63;
    int mh = w & 1, nh = w >> 1;
    int quad = lane >> 4, lx = lane & 15;
    int m0 = blockIdx.x * 64 + mh * 32;
    bf8_t a[2][4];
#pragma unroll
    for (int mt = 0; mt < 2; mt++) {
        int row = m0 + mt * 16 + lx;
        row = row < NN ? row : NN - 1;
#pragma unroll
        for (int kk = 0; kk < 4; kk++) {
            const float4* ap =
                (const float4*)(A + (size_t)row * 128 + kk * 32 + quad * 8);
            float4 u0 = ap[0], u1 = ap[1];
            union { unsigned u[4]; bf8_t v; } t;
            t.u[0] = f2bf_pack(u0.x, u0.y);
            t.u[1] = f2bf_pack(u0.z, u0.w);
            t.u[2] = f2bf_pack(u1.x, u1.y);
            t.u[3] = f2bf_pack(u1.z, u1.w);
            a[mt][kk] = t.v;
        }
    }
    f4_t acc[2][4];
#pragma unroll
    for (int mt = 0; mt < 2; mt++)
#pragma unroll
        for (int nt = 0; nt < 4; nt++) acc[mt][nt] = (f4_t){0.f, 0.f, 0.f, 0.f};
#pragma unroll
    for (int nt = 0; nt < 4; nt++) {
        int ntg = nh * 4 + nt;
#pragma unroll
        for (int kk = 0; kk < 4; kk++) {
            union { uint4 u; bf8_t v; } bb;
            bb.u = btf[(ntg * 4 + kk) * 64 + lane];
            acc[0][nt] = __builtin_amdgcn_mfma_f32_16x16x32_bf16(
                a[0][kk], bb.v, acc[0][nt], 0, 0, 0);
            acc[1][nt] = __builtin_amdgcn_mfma_f32_16x16x32_bf16(
                a[1][kk], bb.v, acc[1][nt], 0, 0, 0);
        }
    }
#pragma unroll
    for (int mt = 0; mt < 2; mt++)
#pragma unroll
        for (int nt = 0; nt < 4; nt++) {
#pragma unroll
            for (int r = 0; r < 4; r++) {
                int row = m0 + mt * 16 + quad * 4 + r;
                if (row < NN)
                    outb[(size_t)row * 128 + (nh * 4 + nt) * 16 + lx] =
                        f2bf1(acc[mt][nt][r]);
            }
        }
}

// ---------------- edge gate via MFMA: h = [mu|mv|f2|f3] @ W1 + b1 ----------
__global__ __launch_bounds__(256) void k_gate(
    const unsigned* __restrict__ mb, const int2* __restrict__ es,
    const uint4* __restrict__ w1f, const float* __restrict__ b1,
    const float* __restrict__ w2, const float* __restrict__ b2,
    float* __restrict__ g_s) {
    int wv = threadIdx.x >> 6, lane = threadIdx.x & 63;
    int e0 = (blockIdx.x * 4 + wv) * 16;
    int quad = lane >> 4, lx = lane & 15;
    int2 sd = es[e0 + lx];
    int node = (quad < 2) ? sd.x : sd.y;
    int half = quad & 1;
    uint4 mu = *(const uint4*)(mb + (unsigned)(node << 3) + (half << 2));
    union { unsigned u[4]; bf8_t v; } a0, a1;
    a0.u[0] = mu.x; a0.u[1] = mu.y; a0.u[2] = mu.z; a0.u[3] = mu.w;
    unsigned o0 = __shfl_xor(mu.x, 32, 64), o1 = __shfl_xor(mu.y, 32, 64);
    unsigned o2 = __shfl_xor(mu.z, 32, 64), o3 = __shfl_xor(mu.w, 32, 64);
    float own[8], oth[8];
    {
        float2 t;
        t = bf2x(mu.x); own[0] = t.x; own[1] = t.y;
        t = bf2x(mu.y); own[2] = t.x; own[3] = t.y;
        t = bf2x(mu.z); own[4] = t.x; own[5] = t.y;
        t = bf2x(mu.w); own[6] = t.x; own[7] = t.y;
        t = bf2x(o0); oth[0] = t.x; oth[1] = t.y;
        t = bf2x(o1); oth[2] = t.x; oth[3] = t.y;
        t = bf2x(o2); oth[4] = t.x; oth[5] = t.y;
        t = bf2x(o3); oth[6] = t.x; oth[7] = t.y;
    }
    float f[8];
#pragma unroll
    for (int j = 0; j < 8; j++)
        f[j] = (quad < 2) ? fabsf(own[j] - oth[j]) : own[j] * oth[j];
#pragma unroll
    for (int q = 0; q < 4; q++) a1.u[q] = f2bf_pack(f[2 * q], f[2 * q + 1]);
    f4_t acc[4];
#pragma unroll
    for (int nt = 0; nt < 4; nt++) {
        float bi = b1[nt * 16 + lx];
        acc[nt] = (f4_t){bi, bi, bi, bi};
    }
#pragma unroll
    for (int nt = 0; nt < 4; nt++) {
        union { uint4 u; bf8_t v; } b0, bb1;
        b0.u = w1f[(nt * 2 + 0) * 64 + lane];
        bb1.u = w1f[(nt * 2 + 1) * 64 + lane];
        acc[nt] = __builtin_amdgcn_mfma_f32_16x16x32_bf16(a0.v, b0.v, acc[nt],
                                                          0, 0, 0);
        acc[nt] = __builtin_amdgcn_mfma_f32_16x16x32_bf16(a1.v, bb1.v, acc[nt],
                                                          0, 0, 0);
    }
    float p[4] = {0.f, 0.f, 0.f, 0.f};
#pragma unroll
    for (int nt = 0; nt < 4; nt++) {
        float w2v = w2[nt * 16 + lx];
#pragma unroll
        for (int r = 0; r < 4; r++)
            p[r] = fmaf(fmaxf(acc[nt][r], 0.0f), w2v, p[r]);
    }
#pragma unroll
    for (int m = 1; m < 16; m <<= 1) {
#pragma unroll
        for (int r = 0; r < 4; r++) p[r] += __shfl_xor(p[r], m, 64);
    }
    if (lx < 4) {
        float g = p[lx] + b2[0];
        g_s[e0 + quad * 4 + lx] = 1.0f / (1.0f + __expf(-g));
    }
}

// ---------------- deg = 1 + row-sum of sorted gates -> dinv (wave/node) ----
__global__ __launch_bounds__(256) void k_deg(const int* __restrict__ rowstart,
                                             const int* __restrict__ count,
                                             const float* __restrict__ g_s,
                                             float* __restrict__ dinv) {
    int n = blockIdx.x * 4 + (threadIdx.x >> 6);
    int lane = threadIdx.x & 63;
    if (n >= NN) return;
    int a = rowstart[n], cnt = count[n];
    float sum = 0.0f;
    for (int c = lane; c < cnt; c += 64) sum += g_s[a + c];
#pragma unroll
    for (int m = 1; m < 64; m <<= 1) sum += __shfl_xor(sum, m, 64);
    if (lane == 0) dinv[n] = rsqrtf(1.0f + sum);
}

// ---------------- MFMA GEMM (layer 1): xw_bf16 = A_bf16 @ W ----------------
__global__ __launch_bounds__(256) void k_mm_conv(
    const ushort_t* __restrict__ A, const uint4* __restrict__ btf,
    ushort_t* __restrict__ outb) {
    int w = threadIdx.x >> 6, lane = threadIdx.x & 63;
    int mh = w & 1, nh = w >> 1;
    int quad = lane >> 4, lx = lane & 15;
    int m0 = blockIdx.x * 64 + mh * 32;
    bf8_t a[2][4];
#pragma unroll
    for (int mt = 0; mt < 2; mt++) {
        int row = m0 + mt * 16 + lx;
        row = row < NN ? row : NN - 1;
#pragma unroll
        for (int kk = 0; kk < 4; kk++)
            a[mt][kk] = *(const bf8_t*)(A + (size_t)row * 128 + kk * 32 + quad * 8);
    }
    f4_t acc[2][4];
#pragma unroll
    for (int mt = 0; mt < 2; mt++)
#pragma unroll
        for (int nt = 0; nt < 4; nt++) acc[mt][nt] = (f4_t){0.f, 0.f, 0.f, 0.f};
#pragma unroll
    for (int nt = 0; nt < 4; nt++) {
        int ntg = nh * 4 + nt;
#pragma unroll
        for (int kk = 0; kk < 4; kk++) {
            union { uint4 u; bf8_t v; } bb;
            bb.u = btf[(ntg * 4 + kk) * 64 + lane];
            acc[0][nt] = __builtin_amdgcn_mfma_f32_16x16x32_bf16(
                a[0][kk], bb.v, acc[0][nt], 0, 0, 0);
            acc[1][nt] = __builtin_amdgcn_mfma_f32_16x16x32_bf16(
                a[1][kk], bb.v, acc[1][nt], 0, 0, 0);
        }
    }
#pragma unroll
    for (int mt = 0; mt < 2; mt++)
#pragma unroll
        for (int nt = 0; nt < 4; nt++) {
#pragma unroll
            for (int r = 0; r < 4; r++) {
                int row = m0 + mt * 16 + quad * 4 + r;
                if (row < NN)
                    outb[(size_t)row * 128 + (nh * 4 + nt) * 16 + lx] =
                        f2bf1(acc[mt][nt][r]);
            }
        }
}

// ---------------- MFMA GEMM head: out = A_bf16 @ head_w + head_b (N=64) ----
__global__ __launch_bounds__(256) void k_mm_head(
    const ushort_t* __restrict__ A, const uint4* __restrict__ btf,
    const float* __restrict__ bias, float* __restrict__ out) {
    int w = threadIdx.x >> 6, lane = threadIdx.x & 63;
    int mh = w & 1, nh = w >> 1;
    int quad = lane >> 4, lx = lane & 15;
    int m0 = blockIdx.x * 64 + mh * 32;
    bf8_t a[2][4];
#pragma unroll
    for (int mt = 0; mt < 2; mt++) {
        int row = m0 + mt * 16 + lx;
        row = row < NN ? row : NN - 1;
#pragma unroll
        for (int kk = 0; kk < 4; kk++)
            a[mt][kk] = *(const bf8_t*)(A + (size_t)row * 128 + kk * 32 + quad * 8);
    }
    f4_t acc[2][2];
#pragma unroll
    for (int mt = 0; mt < 2; mt++)
#pragma unroll
        for (int nt = 0; nt < 2; nt++) acc[mt][nt] = (f4_t){0.f, 0.f, 0.f, 0.f};
#pragma unroll
    for (int nt = 0; nt < 2; nt++) {
        int ntg = nh * 2 + nt;
#pragma unroll
        for (int kk = 0; kk < 4; kk++) {
            union { uint4 u; bf8_t v; } bb;
            bb.u = btf[(ntg * 4 + kk) * 64 + lane];
            acc[0][nt] = __builtin_amdgcn_mfma_f32_16x16x32_bf16(
                a[0][kk], bb.v, acc[0][nt], 0, 0, 0);
            acc[1][nt] = __builtin_amdgcn_mfma_f32_16x16x32_bf16(
                a[1][kk], bb.v, acc[1][nt], 0, 0, 0);
        }
    }
#pragma unroll
    for (int mt = 0; mt < 2; mt++)
#pragma unroll
        for (int nt = 0; nt < 2; nt++) {
            int col = (nh * 2 + nt) * 16 + lx;
            float bs = bias[col];
#pragma unroll
            for (int r = 0; r < 4; r++) {
                int row = m0 + mt * 16 + quad * 4 + r;
                if (row < NN) out[(size_t)row * 64 + col] = acc[mt][nt][r] + bs;
            }
        }
}

// ---------------- fused gather(bf16) + bias + LN + relu + residual ---------
// Best-measured inner loop (R4/R6: 78.2-79.5us, VGPR 20-24); don't touch it.
// wnorm FOLDED IN (kernel deleted): per-edge weight = g_s[e]*dinv[src]
// (L2-resident 4B gather at chunk setup, off the inner gather chain);
// dinv[dst] is row-constant -> init self with dn*xw, end-scale acc *= dn
// (gives dn^2*self + dn*sum as required). Residual: f32 x (L0) or bf16 xcb
// in-place (L1).
__global__ __launch_bounds__(256) void k_aggr(
    const int* __restrict__ rowstart, const int* __restrict__ count,
    const int2* __restrict__ es, const float* __restrict__ g_s,
    const unsigned* __restrict__ xwb, const float* __restrict__ dinv,
    const float* __restrict__ xoldf, const unsigned* __restrict__ xoldb,
    unsigned* __restrict__ xnewb, const float* __restrict__ cb,
    const float* __restrict__ lg, const float* __restrict__ lb,
    const int res_f32) {
    int n = blockIdx.x * 4 + (threadIdx.x >> 6);
    int lane = threadIdx.x & 63;
    if (n >= NN) return;
    float dn = dinv[n];
    unsigned su = xwb[(unsigned)(n << 6) | lane];  // self-loop
    f2v acc;
    acc.x = __uint_as_float(su << 16) * dn;   // end-scale supplies 2nd dn
    acc.y = __uint_as_float(su & 0xffff0000u) * dn;
    int start = rowstart[n], cnt = count[n];
    for (int c = 0; c < cnt; c += 64) {
        int rem = cnt - c;
        int sv = 0; float wv = 0.0f;
        if (lane < rem) {
            sv = es[start + c + lane].x;
            wv = g_s[start + c + lane] * dinv[sv];  // fold dinv[src]
        }
        int m = rem < 64 ? rem : 64;
        int j = 0;
        for (; j + 8 <= m; j += 8) {  // 8 independent gathers in flight
            unsigned u[8]; float w[8];
#pragma unroll
            for (int q = 0; q < 8; q++) {
                int s = __shfl(sv, j + q, 64);
                w[q] = __shfl(wv, j + q, 64);
                u[q] = xwb[(unsigned)(s << 6) | lane];
            }
#pragma unroll
            for (int q = 0; q < 8; q++) {
                f2v v;
                v.x = __uint_as_float(u[q] << 16);
                v.y = __uint_as_float(u[q] & 0xffff0000u);
                acc += v * w[q];
            }
        }
        for (; j + 4 <= m; j += 4) {
            unsigned u[4]; float w[4];
#pragma unroll
            for (int q = 0; q < 4; q++) {
                int s = __shfl(sv, j + q, 64);
                w[q] = __shfl(wv, j + q, 64);
                u[q] = xwb[(unsigned)(s << 6) | lane];
            }
#pragma unroll
            for (int q = 0; q < 4; q++) {
                f2v v;
                v.x = __uint_as_float(u[q] << 16);
                v.y = __uint_as_float(u[q] & 0xffff0000u);
                acc += v * w[q];
            }
        }
        for (; j < m; j++) {
            int s = __shfl(sv, j, 64);
            float w = __shfl(wv, j, 64);
            unsigned u = xwb[(unsigned)(s << 6) | lane];
            f2v v;
            v.x = __uint_as_float(u << 16);
            v.y = __uint_as_float(u & 0xffff0000u);
            acc += v * w;
        }
    }
    acc.x *= dn; acc.y *= dn;  // row-constant dinv[dst]
    float2 cbv = ((const float2*)cb)[lane];
    acc.x += cbv.x; acc.y += cbv.y;
    float s1 = acc.x + acc.y, s2 = acc.x * acc.x + acc.y * acc.y;
#pragma unroll
    for (int mm = 1; mm < 64; mm <<= 1) {
        s1 += __shfl_xor(s1, mm, 64);
        s2 += __shfl_xor(s2, mm, 64);
    }
    float mean = s1 * (1.0f / 128.0f);
    float var = s2 * (1.0f / 128.0f) - mean * mean;
    float rstd = rsqrtf(var + 1e-5f);
    float2 lgv = ((const float2*)lg)[lane];
    float2 lbv = ((const float2*)lb)[lane];
    float y0 = fmaxf((acc.x - mean) * rstd * lgv.x + lbv.x, 0.0f);
    float y1 = fmaxf((acc.y - mean) * rstd * lgv.y + lbv.y, 0.0f);
    float2 xo;
    if (res_f32)
        xo = ((const float2*)xoldf)[(size_t)n * 64 + lane];
    else
        xo = bf2x(xoldb[(unsigned)(n << 6) | lane]);
    float o0 = xo.x + y0, o1 = xo.y + y1;
    xnewb[(size_t)n * 64 + lane] = f2bf_pack(o0, o1);
}

extern "C" void kernel_launch(void* const* d_in, const int* in_sizes, int n_in,
                              void* d_out, int out_size, void* d_ws,
                              size_t ws_size, hipStream_t stream) {
    const float* x = (const float*)d_in[0];
    const float* motif = (const float*)d_in[1];
    const void* ei = d_in[2];
    const float* gw1 = (const float*)d_in[3];
    const float* gb1 = (const float*)d_in[4];
    const float* gw2 = (const float*)d_in[5];
    const float* gb2 = (const float*)d_in[6];
    const float* cw = (const float*)d_in[7];   // [2,128,128]
    const float* cb = (const float*)d_in[8];   // [2,128]
    const float* lg = (const float*)d_in[9];
    const float* lb = (const float*)d_in[10];
    const float* hw = (const float*)d_in[11];  // [128,64]
    const float* hb = (const float*)d_in[12];
    float* out = (float*)d_out;

    float* ws = (float*)d_ws;
    size_t o = 0;
    float* dinv = ws + o; o += NN;
    int* flag = (int*)(ws + o); o += 64;  // unused (layout stability)
    int* count = (int*)(ws + o); o += NN;
    int* rowstart = (int*)(ws + o); o += NN;
    int* cursor = (int*)(ws + o); o += NN;
    int* bsum = (int*)(ws + o); o += 64;
    int* boffs = (int*)(ws + o); o += 64;  // unused (layout stability)
    int2* es = (int2*)(ws + o); o += 2 * (size_t)NE;
    float* g_s = ws + o; o += NE;
    unsigned* xwb = (unsigned*)(ws + o); o += (size_t)NN * 64;  // bf16 xw
    float* xc = ws + o; o += (size_t)NN * IND;  // hosts s32/d32 only
    unsigned* xcb = (unsigned*)(ws + o); o += (size_t)NN * 64;  // bf16 xc
    unsigned* btf = (unsigned*)(ws + o); o += 22528;            // frag-packed W
    unsigned* mb = (unsigned*)(ws + o); o += (size_t)NN * 8;    // bf16 motif
    (void)flag; (void)boffs;

    int* s32 = (int*)xc;
    int* d32 = (int*)xc + NE;

    hipMemsetAsync(count, 0, NN * sizeof(int), stream);
    // fused: cvt (inline int64/int32 detect) | motif bf16 pack | weight pack
    k_front<<<CVT_BLKS + MPREP_BLKS + PREP_BLKS, 256, 0, stream>>>(
        ei, s32, d32, count, motif, mb, cw, hw, gw1, btf);

    // counting sort by dst -> CSR (scan2 folded into scan3)
    k_scan1<<<SCAN1_BLKS, 256, 0, stream>>>(count, rowstart, bsum);
    k_scan3<<<(NN + 255) / 256, 256, 0, stream>>>(rowstart, bsum, cursor);
    // CSR fill standalone (low VGPR -> high occupancy for atomic latency)
    k_fill<<<FILL_BLKS, 256, 0, stream>>>(s32, d32, cursor, es);
    // L0 GEMM standalone (~17us; fusion homes measured as net losers)
    k_mm_conv_f32<<<GMM_BLKS, 256, 0, stream>>>(x, (const uint4*)btf,
                                                (ushort_t*)xwb);

    // gate writes RAW sigmoid gates; deg consumes them directly.
    k_gate<<<NE / 64, 256, 0, stream>>>(mb, es, (const uint4*)(btf + 20480),
                                        gb1, gw2, gb2, g_s);
    k_deg<<<(NN + 3) / 4, 256, 0, stream>>>(rowstart, count, g_s, dinv);
    // (wnorm eliminated: dinv folded into k_aggr)

    // layer 0: residual from f32 x, output bf16 only
    k_aggr<<<(NN + 3) / 4, 256, 0, stream>>>(rowstart, count, es, g_s, xwb,
                                             dinv, x, (const unsigned*)0, xcb,
                                             cb, lg, lb, 1);
    // layer 1: residual from bf16 xcb (in-place)
    k_mm_conv<<<GMM_BLKS, 256, 0, stream>>>((const ushort_t*)xcb,
                                            (const uint4*)(btf + 8192),
                                            (ushort_t*)xwb);
    k_aggr<<<(NN + 3) / 4, 256, 0, stream>>>(rowstart, count, es, g_s, xwb,
                                             dinv, (const float*)0, xcb, xcb,
                                             cb + IND, lg + IND, lb + IND, 0);

    k_mm_head<<<GMM_BLKS, 256, 0, stream>>>((const ushort_t*)xcb,
                                            (const uint4*)(btf + 16384), hb,
                                            out);
}